// Round 1
// baseline (340.664 us; speedup 1.0000x reference)
//
#include <hip/hip_runtime.h>

#define DHW   192
#define R     8
#define NPTS  16

// Block: 192 threads = 4 y-rows x 48 float4-wide x positions.
// Grid:  bs * 192 (z) * 48 (y-quads) = 36864 blocks.
__global__ __launch_bounds__(192) void clickmap_kernel(
    const float* __restrict__ coords,   // (4,16,3) float32: x,y,z
    const int*   __restrict__ labels,   // (4,16) int32 in {-1,0,1}
    float*       __restrict__ out)      // 12*192^3 floats
{
    const int bid = blockIdx.x;
    const int yq  = bid % 48;
    const int z   = (bid / 48) % DHW;
    const int b   = bid / (48 * DHW);
    const int tid = threadIdx.x;
    const int row = tid / 48;        // 0..3
    const int xi  = tid % 48;        // 0..47
    const int y   = yq * 4 + row;
    const int x0  = xi * 4;

    __shared__ int s_px[NPTS], s_py[NPTS], s_pz[NPTS], s_lab[NPTS];
    __shared__ unsigned s_mask;

    // Wave 0 stages points + builds the candidate bitmask for this block.
    if (tid < 64) {
        bool cand = false;
        if (tid < NPTS) {
            const int j   = tid;
            const int lab = labels[b * NPTS + j];
            const int px  = (int)coords[(b * NPTS + j) * 3 + 0];
            const int py  = (int)coords[(b * NPTS + j) * 3 + 1];
            const int pz  = (int)coords[(b * NPTS + j) * 3 + 2];
            s_px[j] = px; s_py[j] = py; s_pz[j] = pz; s_lab[j] = lab;
            const int y0 = yq * 4;
            cand = (lab == 0 || lab == 1) &&
                   (pz >= z - R  && pz <= z + R) &&
                   (py >= y0 - R && py <= y0 + 3 + R);
        }
        unsigned long long m = __ballot(cand);
        if (tid == 0) s_mask = (unsigned)m;
    }
    __syncthreads();

    const unsigned mask = s_mask;

    const size_t vol  = (size_t)DHW * DHW * DHW;
    const size_t posi = (((size_t)(b * 2 + 0) * DHW + z) * DHW + y) * DHW + x0;
    const size_t negi = posi + vol;
    const size_t deni = (size_t)8 * vol + ((((size_t)b * DHW + z) * DHW + y) * DHW + x0);

    const float4 zero4 = make_float4(0.f, 0.f, 0.f, 0.f);
    // dense_embeddings: always zero
    *(float4*)(out + deni) = zero4;

    if (mask == 0u) {           // fast path: no point touches this tile
        *(float4*)(out + posi) = zero4;
        *(float4*)(out + negi) = zero4;
        return;
    }

    float pv[4] = {0.f, 0.f, 0.f, 0.f};
    float nv[4] = {0.f, 0.f, 0.f, 0.f};
    bool  fp[4] = {false, false, false, false};
    bool  fn[4] = {false, false, false, false};

    // Reverse scan over this batch's points: last writer in the reference's
    // sequential scan wins, per channel, per voxel.
    for (int j = NPTS - 1; j >= 0; --j) {
        if (!((mask >> j) & 1u)) continue;
        const int lab = s_lab[j];
        const int dz  = z + R - s_pz[j];
        const int dy  = y + R - s_py[j];
        if ((unsigned)dz > 16u || (unsigned)dy > 16u) continue;
        const int rz = dz - R, ry = dy - R;
        const int r2yz = rz * rz + ry * ry;
        #pragma unroll
        for (int e = 0; e < 4; ++e) {
            const int dx = x0 + e + R - s_px[j];
            if ((unsigned)dx > 16u) continue;
            const int rx = dx - R;
            const int r2 = r2yz + rx * rx;
            // reference zeroes entries with h < eps*h.max()  <=>  r2 >= 128
            const float v = (r2 >= 128) ? 0.f : __expf((float)r2 * -0.125f);
            if (lab == 1) { if (!fp[e]) { pv[e] = v; fp[e] = true; } }
            else          { if (!fn[e]) { nv[e] = v; fn[e] = true; } }
        }
    }

    *(float4*)(out + posi) = make_float4(pv[0], pv[1], pv[2], pv[3]);
    *(float4*)(out + negi) = make_float4(nv[0], nv[1], nv[2], nv[3]);
}

extern "C" void kernel_launch(void* const* d_in, const int* in_sizes, int n_in,
                              void* d_out, int out_size, void* d_ws, size_t ws_size,
                              hipStream_t stream) {
    const float* coords = (const float*)d_in[0];  // 4*16*3 floats
    const int*   labels = (const int*)d_in[1];    // 4*16 ints
    float*       out    = (float*)d_out;          // 12*192^3 floats

    const int grid = 4 * DHW * 48;                // 36864 blocks
    clickmap_kernel<<<grid, 192, 0, stream>>>(coords, labels, out);
}